// Round 8
// baseline (1564.378 us; speedup 1.0000x reference)
//
#include <hip/hip_runtime.h>
#include <stdint.h>

#define HID 256
#define CAP 16

typedef __attribute__((ext_vector_type(8))) short bf16x8;   // 8 bf16 (4 VGPRs)
typedef __attribute__((ext_vector_type(4))) float f32x4;
typedef __attribute__((ext_vector_type(2))) float f32x2;
typedef __attribute__((ext_vector_type(4))) unsigned short u16x4;
typedef __attribute__((ext_vector_type(4))) unsigned char u8x4;

__device__ __forceinline__ float bf2f(unsigned short u) {
    union { unsigned int i; float f; } v; v.i = ((unsigned int)u) << 16; return v.f;
}
__device__ __forceinline__ unsigned short f2bf(float f) {
    union { float f; unsigned int i; } v; v.f = f;
    unsigned int r = (v.i + 0x7fffu + ((v.i >> 16) & 1u)) >> 16;
    return (unsigned short)r;
}
// ---- software fp8 e4m3fn fallbacks (exact w.r.t. the hw path) ----
__device__ __forceinline__ float fp82f_sw(unsigned char b) {
    unsigned int s = (unsigned int)(b & 0x80) << 24;
    int e = (b >> 3) & 0xF;
    int m = b & 7;
    float v;
    if (e) v = __uint_as_float(((unsigned int)(e + 120) << 23) | ((unsigned int)m << 20));
    else   v = (float)m * 0.001953125f;
    return __uint_as_float(__float_as_uint(v) | s);
}
__device__ __forceinline__ unsigned char f2fp8_sw(float x) {
    unsigned int bits = __float_as_uint(x);
    unsigned char s = (unsigned char)((bits >> 24) & 0x80);
    float ax = fabsf(x);
    if (!(ax >= 0.001953125f)) {
        int n = (int)rintf(ax * 512.f);
        return s | (unsigned char)n;
    }
    if (ax >= 448.f) return s | 0x7E;
    int ex; float mant = frexpf(ax, &ex);
    int e = ex + 6;
    if (e >= 1) {
        int q = (int)rintf(mant * 16.f);
        if (q == 16) { q = 8; ++e; }
        if (e > 15 || (e == 15 && q > 14)) return s | 0x7E;
        return s | (unsigned char)((e << 3) | (q - 8));
    } else {
        int n = (int)rintf(ax * 512.f);
        if (n >= 8) return s | 0x08;
        return s | (unsigned char)n;
    }
}
// ---- hardware fp8 conversion (gfx950: OCP e4m3fn) ----
__device__ __forceinline__ unsigned char f2fp8(float x) {
#if __has_builtin(__builtin_amdgcn_cvt_pk_fp8_f32)
    return (unsigned char)(__builtin_amdgcn_cvt_pk_fp8_f32(x, x, 0, false) & 0xff);
#else
    return f2fp8_sw(x);
#endif
}
__device__ __forceinline__ f32x4 fp8x4_to_f32(unsigned int u) {
#if __has_builtin(__builtin_amdgcn_cvt_pk_f32_fp8)
    f32x2 a = __builtin_amdgcn_cvt_pk_f32_fp8(u, false);
    f32x2 b = __builtin_amdgcn_cvt_pk_f32_fp8(u, true);
    f32x4 r; r[0] = a.x; r[1] = a.y; r[2] = b.x; r[3] = b.y;
    return r;
#else
    f32x4 r;
    #pragma unroll
    for (int q = 0; q < 4; ++q) r[q] = fp82f_sw((u >> (8 * q)) & 0xff);
    return r;
#endif
}
// 8 fp8 bytes -> 8 bf16 (exact: every e4m3fn value is representable in bf16)
__device__ __forceinline__ bf16x8 fp8x8_to_bf16x8(uint2 raw) {
#if __has_builtin(__builtin_amdgcn_cvt_pk_f32_fp8)
    f32x2 p0 = __builtin_amdgcn_cvt_pk_f32_fp8(raw.x, false);
    f32x2 p1 = __builtin_amdgcn_cvt_pk_f32_fp8(raw.x, true);
    f32x2 p2 = __builtin_amdgcn_cvt_pk_f32_fp8(raw.y, false);
    f32x2 p3 = __builtin_amdgcn_cvt_pk_f32_fp8(raw.y, true);
    union { unsigned int u[4]; bf16x8 v; } cv;
    cv.u[0] = (__float_as_uint(p0.x) >> 16) | (__float_as_uint(p0.y) & 0xffff0000u);
    cv.u[1] = (__float_as_uint(p1.x) >> 16) | (__float_as_uint(p1.y) & 0xffff0000u);
    cv.u[2] = (__float_as_uint(p2.x) >> 16) | (__float_as_uint(p2.y) & 0xffff0000u);
    cv.u[3] = (__float_as_uint(p3.x) >> 16) | (__float_as_uint(p3.y) & 0xffff0000u);
    return cv.v;
#else
    union { unsigned short u[8]; bf16x8 v; } cv;
    #pragma unroll
    for (int q = 0; q < 4; ++q) cv.u[q]     = f2bf(fp82f_sw((raw.x >> (8 * q)) & 0xff));
    #pragma unroll
    for (int q = 0; q < 4; ++q) cv.u[4 + q] = f2bf(fp82f_sw((raw.y >> (8 * q)) & 0xff));
    return cv.v;
#endif
}

// ---------------- utility / prep kernels ----------------

__global__ void k_zero_f(float* __restrict__ p, size_t n) {
    size_t i = (size_t)blockIdx.x * 256 + threadIdx.x;
    if (i < n) p[i] = 0.f;
}
__global__ void k_diag(float* __restrict__ out, float v) {
    if (blockIdx.x == 0 && threadIdx.x == 0) out[0] = v;
}

// one-shot init: zero na (fp32 N*HID), cnt_lg[E], cnt_nd[N], gcnt[G]; gstart[G]=N
__global__ void k_init(float* __restrict__ na, size_t nna,
                       int* __restrict__ cnt_lg, int E,
                       int* __restrict__ cnt_nd, int N,
                       int* __restrict__ gcnt, int* __restrict__ gstart, int G) {
    size_t i = (size_t)blockIdx.x * 256 + threadIdx.x;
    if (i < nna) na[i] = 0.f;
    if (i < (size_t)E) cnt_lg[i] = 0;
    if (i < (size_t)N) cnt_nd[i] = 0;
    if (i < (size_t)G) { gcnt[i] = 0; gstart[i] = N; }
}

// node_alpha[tgt[t]] += tree_mess[t]
__global__ void k_scatter_alpha(const float* __restrict__ tm, const int* __restrict__ tgt,
                                float* __restrict__ na, int T) {
    int t = blockIdx.x;
    if (t >= T) return;
    int c = threadIdx.x;
    atomicAdd(&na[(size_t)tgt[t] * HID + c], tm[(size_t)t * HID + c]);
}

__global__ void k_f2fp8(const float* __restrict__ in, unsigned char* __restrict__ out, size_t n) {
    size_t i = (size_t)blockIdx.x * 256 + threadIdx.x;
    if (i < n) out[i] = f2fp8(in[i]);
}

// Wt_i[n][k] (256 x 64): k<40 -> W_i[k][n], else 0   (bf16)
__global__ void k_wt_i(const float* __restrict__ W, unsigned short* __restrict__ Wt) {
    int i = blockIdx.x * 256 + threadIdx.x;   // 256*64
    int n = i >> 6, k = i & 63;
    Wt[i] = f2bf((k < 40) ? W[k * HID + n] : 0.f);
}
// Wt_hi[n][k] (256 x 320): k<256 -> W_h[k][n]; k-256<40 -> W_i[k-256][n]; else 0
__global__ void k_wt_hi(const float* __restrict__ Wh, const float* __restrict__ Wi,
                        unsigned short* __restrict__ Wt) {
    int i = blockIdx.x * 256 + threadIdx.x;   // 256*320
    int n = i / 320, k = i % 320;
    float v;
    if (k < 256) v = Wh[(size_t)k * HID + n];
    else if (k < 296) v = Wi[(size_t)(k - 256) * HID + n];
    else v = 0.f;
    Wt[i] = f2bf(v);
}
// Wt_o[n][k] (256 x 320): k<256 -> W_o[35+k][n]; k-256<35 -> W_o[k-256][n]; else 0
__global__ void k_wt_o(const float* __restrict__ W, unsigned short* __restrict__ Wt) {
    int i = blockIdx.x * 256 + threadIdx.x;   // 256*320
    int n = i / 320, k = i % 320;
    float v;
    if (k < 256) v = W[(size_t)(35 + k) * HID + n];
    else if (k < 291) v = W[(size_t)(k - 256) * HID + n];
    else v = 0.f;
    Wt[i] = f2bf(v);
}

// A1[e][0..63] fp8: k<35 node_x[src][k], 35..39 bond_x[e][k-35], else 0
__global__ void k_a1(const float* __restrict__ nx, const float* __restrict__ bx,
                     const int* __restrict__ esrc, unsigned char* __restrict__ A1, int E) {
    int i = blockIdx.x * 256 + threadIdx.x;
    if (i >= E * 64) return;
    int e = i >> 6, k = i & 63;
    float v = 0.f;
    if (k < 35) v = nx[(size_t)esrc[e] * 35 + k];
    else if (k < 40) v = bx[(size_t)e * 5 + (k - 35)];
    A1[i] = f2fp8(v);
}

// X1[v][0..63] fp8: k<35 node_x[v][k], else 0
__global__ void k_x1(const float* __restrict__ nx, unsigned char* __restrict__ X1, int N) {
    int i = blockIdx.x * 256 + threadIdx.x;
    if (i >= N * 64) return;
    int v = i >> 6, k = i & 63;
    X1[i] = f2fp8((k < 35) ? nx[(size_t)v * 35 + k] : 0.f);
}

// bucket fill
__global__ void k_fill(const int* __restrict__ dst, const int* __restrict__ val,
                       int* __restrict__ cnt, int* __restrict__ bkt, int n, int useval) {
    int i = blockIdx.x * 256 + threadIdx.x;
    if (i >= n) return;
    int d = dst[i];
    int p = atomicAdd(&cnt[d], 1);
    if (p < CAP) bkt[(size_t)d * CAP + p] = useval ? val[i] : i;
}

__global__ void k_gfill(const int* __restrict__ gid, int* __restrict__ gstart,
                        int* __restrict__ gcnt, int N) {
    int i = blockIdx.x * 256 + threadIdx.x;
    if (i >= N) return;
    int g = gid[i];
    atomicAdd(&gcnt[g], 1);
    atomicMin(&gstart[g], i);
}

// ---------------- fused gather + split-A GEMM ----------------
// C[M,256] = [Agath (K1 cols) | Aq (KTOT-K1 cols, fp8)] @ B[256][KTOT]^T  (B bf16)
// K1>0: A rows are computed on the fly during staging:
//   Arow[ar] = alpha[esrc?esrc[ar]:ar] + sum_{j<cnt[ar]} msgsrc[bkt[ar*CAP+j]]
// (fp8 storage, fp32 sum, bf16 into LDS — no intermediate materialization.)
// 128x128 tile, 4 waves 2x2, 4x4 of 16x16x32 bf16 MFMAs, BK=64.
// LDS rows padded to 72 elements (144 B -> 2-way bank aliasing = free).
// Per-row degree + first 4 bucket indices preloaded before the K-loop;
// prefetch of tile kc+1 overlaps tile kc's MFMA phase.
// EPI 0: relu(C); EPI 1: relu(C + bias[col]).  OUTF8: store fp8 else bf16.
template<int K1, int KTOT, int EPI, bool OUTF8>
__global__ __launch_bounds__(256)
void gemm2(const unsigned char* __restrict__ msgsrc,
           const unsigned char* __restrict__ alpha,
           const int* __restrict__ esrc,
           const int* __restrict__ cnt,
           const int* __restrict__ bkt,
           const unsigned char* __restrict__ Aq, int lda2,
           const unsigned short* __restrict__ B, int M,
           void* __restrict__ out, const float* __restrict__ bias)
{
    constexpr int NKC = KTOT / 64;
    constexpr int LDP = 72;
    __shared__ unsigned short Als[128 * LDP];
    __shared__ unsigned short Bls[128 * LDP];
    const int tid  = threadIdx.x;
    const int lane = tid & 63;
    const int wid  = tid >> 6;
    const int wm = wid & 1, wn = wid >> 1;
    const int row0 = blockIdx.x * 128;
    const int col0 = blockIdx.y * 128;
    const int l15  = lane & 15;
    const int quad = lane >> 4;

    f32x4 acc[4][4] = {};

    const int sr = tid >> 3;          // 0..31
    const int sc = (tid & 7) * 8;     // element col within 64

    // ---- per-row gather metadata, loaded once ----
    int arr[4], arow_[4], dg[4];
    int4 b0[4];
    if (K1 > 0) {
        #pragma unroll
        for (int t = 0; t < 4; ++t) {
            int ar = row0 + t * 32 + sr; if (ar > M - 1) ar = M - 1;
            arr[t] = ar;
            int d = cnt[ar]; if (d > CAP) d = CAP;
            dg[t] = d;
            b0[t] = *(const int4*)(bkt + (size_t)ar * CAP);
            arow_[t] = esrc ? esrc[ar] : ar;
        }
    }

    bf16x8 pa[4], pb[4];
    auto loadAB = [&](int kc) {
        const int kbase = kc * 64;
        #pragma unroll
        for (int t = 0; t < 4; ++t) {
            if (K1 > 0 && kbase < K1) {
                // fused gather: alpha + sum(msg rows), fp32 accumulate
                const int kofs = kbase + sc;
                uint2 av = *(const uint2*)(alpha + (size_t)arow_[t] * HID + kofs);
                f32x4 s0 = fp8x4_to_f32(av.x);
                f32x4 s1 = fp8x4_to_f32(av.y);
                int d = dg[t];
                int4 bi = b0[t];
                for (int base = 0; base < d; base += 4) {
                    if (base) bi = *(const int4*)(bkt + (size_t)arr[t] * CAP + base);
                    int rem = d - base;
                    int i0 = bi.x;
                    int i1 = (rem > 1) ? bi.y : bi.x;
                    int i2 = (rem > 2) ? bi.z : bi.x;
                    int i3 = (rem > 3) ? bi.w : bi.x;
                    uint2 m0 = *(const uint2*)(msgsrc + (size_t)i0 * HID + kofs);
                    uint2 m1 = *(const uint2*)(msgsrc + (size_t)i1 * HID + kofs);
                    uint2 m2 = *(const uint2*)(msgsrc + (size_t)i2 * HID + kofs);
                    uint2 m3 = *(const uint2*)(msgsrc + (size_t)i3 * HID + kofs);
                    {   f32x4 vx = fp8x4_to_f32(m0.x), vy = fp8x4_to_f32(m0.y);
                        #pragma unroll
                        for (int k = 0; k < 4; ++k) { s0[k] += vx[k]; s1[k] += vy[k]; } }
                    if (rem > 1) { f32x4 vx = fp8x4_to_f32(m1.x), vy = fp8x4_to_f32(m1.y);
                        #pragma unroll
                        for (int k = 0; k < 4; ++k) { s0[k] += vx[k]; s1[k] += vy[k]; } }
                    if (rem > 2) { f32x4 vx = fp8x4_to_f32(m2.x), vy = fp8x4_to_f32(m2.y);
                        #pragma unroll
                        for (int k = 0; k < 4; ++k) { s0[k] += vx[k]; s1[k] += vy[k]; } }
                    if (rem > 3) { f32x4 vx = fp8x4_to_f32(m3.x), vy = fp8x4_to_f32(m3.y);
                        #pragma unroll
                        for (int k = 0; k < 4; ++k) { s0[k] += vx[k]; s1[k] += vy[k]; } }
                }
                union { unsigned short u[8]; bf16x8 v; } cv;
                #pragma unroll
                for (int k = 0; k < 4; ++k) { cv.u[k] = f2bf(s0[k]); cv.u[4 + k] = f2bf(s1[k]); }
                pa[t] = cv.v;
            } else {
                int ar = row0 + t * 32 + sr; if (ar > M - 1) ar = M - 1;
                const int kofs = kbase - K1 + sc;
                uint2 raw = *(const uint2*)(Aq + (size_t)ar * lda2 + kofs);
                pa[t] = fp8x8_to_bf16x8(raw);
            }
            pb[t] = *(const bf16x8*)(B + (size_t)(col0 + t * 32 + sr) * KTOT + kc * 64 + sc);
        }
    };

    loadAB(0);
    #pragma unroll
    for (int kc = 0; kc < NKC; ++kc) {
        #pragma unroll
        for (int t = 0; t < 4; ++t) {
            *(bf16x8*)&Als[(t * 32 + sr) * LDP + sc] = pa[t];
            *(bf16x8*)&Bls[(t * 32 + sr) * LDP + sc] = pb[t];
        }
        __syncthreads();
        if (kc + 1 < NKC) loadAB(kc + 1);   // prefetch (incl. gather) overlaps MFMA below
        #pragma unroll
        for (int kk = 0; kk < 64; kk += 32) {
            bf16x8 af[4], bfr[4];
            #pragma unroll
            for (int i = 0; i < 4; ++i)
                af[i] = *(const bf16x8*)&Als[(wm * 64 + i * 16 + l15) * LDP + kk + quad * 8];
            #pragma unroll
            for (int j = 0; j < 4; ++j)
                bfr[j] = *(const bf16x8*)&Bls[(wn * 64 + j * 16 + l15) * LDP + kk + quad * 8];
            #pragma unroll
            for (int i = 0; i < 4; ++i)
                #pragma unroll
                for (int j = 0; j < 4; ++j)
                    acc[i][j] = __builtin_amdgcn_mfma_f32_16x16x32_bf16(af[i], bfr[j], acc[i][j], 0, 0, 0);
        }
        __syncthreads();
    }

    // epilogue: C/D layout col = lane&15, row = quad*4 + reg
    #pragma unroll
    for (int i = 0; i < 4; ++i) {
        int rbase = row0 + wm * 64 + i * 16 + quad * 4;
        #pragma unroll
        for (int r = 0; r < 4; ++r) {
            int row = rbase + r;
            if (row >= M) continue;
            #pragma unroll
            for (int j = 0; j < 4; ++j) {
                int col = col0 + wn * 64 + j * 16 + l15;
                float v = acc[i][j][r];
                if (EPI == 1) v += bias[col];
                v = v > 0.f ? v : 0.f;
                if (OUTF8) ((unsigned char*)out)[(size_t)row * HID + col] = f2fp8(v);
                else       ((unsigned short*)out)[(size_t)row * HID + col] = f2bf(v);
            }
        }
    }
}

// per-graph mean (graph_ids sorted -> contiguous rows)
__global__ void k_gmean(const unsigned short* __restrict__ h, const int* __restrict__ gstart,
                        const int* __restrict__ gcnt, float* __restrict__ out, int G) {
    int g = blockIdx.x;
    int c = threadIdx.x;
    int st = gstart[g], n = gcnt[g];
    float s = 0.f;
    for (int r = 0; r < n; ++r) s += bf2f(h[(size_t)(st + r) * HID + c]);
    out[(size_t)g * HID + c] = (n > 0) ? s / (float)n : 0.f;
}

// ---------------- launch ----------------
extern "C" void kernel_launch(void* const* d_in, const int* in_sizes, int n_in,
                              void* d_out, int out_size, void* d_ws, size_t ws_size,
                              hipStream_t stream)
{
    const float* node_x    = (const float*)d_in[0];
    const float* bond_x    = (const float*)d_in[1];
    const float* tree_mess = (const float*)d_in[2];
    const float* W_i       = (const float*)d_in[3];
    const float* W_h       = (const float*)d_in[4];
    const float* W_o       = (const float*)d_in[5];
    const float* b_o       = (const float*)d_in[6];
    const int* edge_src    = (const int*)d_in[7];
    const int* edge_dst    = (const int*)d_in[8];
    const int* lg_src      = (const int*)d_in[9];
    const int* lg_dst      = (const int*)d_in[10];
    const int* tgt_nodes   = (const int*)d_in[11];
    const int* graph_ids   = (const int*)d_in[12];

    const int N = in_sizes[0] / 35;
    const int E = in_sizes[1] / 5;
    const int T = in_sizes[2] / HID;
    const int L = in_sizes[9];
    const int G = out_size / HID;

    auto rup = [](size_t b) { return (b + 255) & ~(size_t)255; };
    const size_t szMsg = (size_t)E * HID;        // msg fp8 (each ping-pong buffer)
    const size_t szMbN = (size_t)N * HID * 2;    // h bf16
    const size_t R_msgB = rup(szMsg > szMbN ? szMsg : szMbN);  // msgB
    const size_t R_msgA = rup(szMsg > szMbN ? szMsg : szMbN);  // msgA / h
    const size_t R_al  = rup((size_t)N * HID);   // alpha fp8
    const size_t R_a1  = rup((size_t)E * 64);    // A1/X1 fp8
    const size_t need = R_msgB + R_msgA + R_al + R_a1
        + rup(256 * 64 * 2) + rup((size_t)256 * 320 * 2) * 2
        + rup((size_t)E * 4) + rup((size_t)E * CAP * 4)
        + rup((size_t)N * 4) + rup((size_t)N * CAP * 4)
        + rup((size_t)G * 4) * 2;
    // na (fp32, N*HID*4) aliases R_msgB+R_msgA (adjacent, 2*E*HID >= N*HID*4)

    if (need > ws_size) {
        k_zero_f<<<(out_size + 255) / 256, 256, 0, stream>>>((float*)d_out, (size_t)out_size);
        k_diag<<<1, 64, 0, stream>>>((float*)d_out, (float)(ws_size >> 20));
        return;
    }

    char* w = (char*)d_ws;
    auto alloc = [&](size_t bytes) { char* p = w; w += (bytes + 255) & ~(size_t)255; return p; };
    char* r_msgB = (char*)alloc(R_msgB);
    char* r_msgA = (char*)alloc(R_msgA);
    char* r_al   = (char*)alloc(R_al);
    char* r_a1   = (char*)alloc(R_a1);
    unsigned short* Wt_i  = (unsigned short*)alloc(256 * 64 * 2);
    unsigned short* Wt_hi = (unsigned short*)alloc((size_t)256 * 320 * 2);
    unsigned short* Wt_o  = (unsigned short*)alloc((size_t)256 * 320 * 2);
    int* cnt_lg = (int*)alloc((size_t)E * 4);
    int* bkt_lg = (int*)alloc((size_t)E * CAP * 4);
    int* cnt_nd = (int*)alloc((size_t)N * 4);
    int* bkt_nd = (int*)alloc((size_t)N * CAP * 4);
    int* gstart = (int*)alloc((size_t)G * 4);
    int* gcnt   = (int*)alloc((size_t)G * 4);

    float*          na    = (float*)r_msgB;            // spans r_msgB..r_msgA (adjacent)
    unsigned char*  msgA  = (unsigned char*)r_msgA;
    unsigned char*  msgB  = (unsigned char*)r_msgB;
    unsigned short* h     = (unsigned short*)r_msgA;   // msgA dead at final GEMM
    unsigned char*  alpha = (unsigned char*)r_al;
    unsigned char*  A1    = (unsigned char*)r_a1;
    unsigned char*  X1    = (unsigned char*)r_a1;

    // ---- init (single merged kernel) ----
    k_init<<<(int)(((size_t)N * HID + 255) / 256), 256, 0, stream>>>(
        na, (size_t)N * HID, cnt_lg, E, cnt_nd, N, gcnt, gstart, G);

    k_wt_i<<<64, 256, 0, stream>>>(W_i, Wt_i);
    k_wt_hi<<<320, 256, 0, stream>>>(W_h, W_i, Wt_hi);
    k_wt_o<<<320, 256, 0, stream>>>(W_o, Wt_o);
    k_scatter_alpha<<<T, 256, 0, stream>>>(tree_mess, tgt_nodes, na, T);
    k_fill<<<(L + 255) / 256, 256, 0, stream>>>(lg_dst, lg_src, cnt_lg, bkt_lg, L, 1);
    k_fill<<<(E + 255) / 256, 256, 0, stream>>>(edge_dst, (const int*)nullptr, cnt_nd, bkt_nd, E, 0);
    k_gfill<<<(N + 255) / 256, 256, 0, stream>>>(graph_ids, gstart, gcnt, N);
    k_f2fp8<<<(int)(((size_t)N * HID + 255) / 256), 256, 0, stream>>>(na, alpha, (size_t)N * HID);
    k_a1<<<(E * 64 + 255) / 256, 256, 0, stream>>>(node_x, bond_x, edge_src, A1, E);
    // na now dead; msgA/msgB regions free

    dim3 gE((E + 127) / 128, 2), gN((N + 127) / 128, 2);

    // msg0 = relu(A1 @ W_i)   [fp8 out -> msgA]
    gemm2<0, 64, 0, true><<<gE, 256, 0, stream>>>(
        nullptr, nullptr, nullptr, nullptr, nullptr, A1, 64, Wt_i, E, msgA, nullptr);

    // 3 loopy-BP iters, fused gather: msg_next = relu([alpha[src]+gather(msg) | A1] @ Wt_hi^T)
    unsigned char* cur = msgA;
    unsigned char* nxt = msgB;
    for (int it = 0; it < 3; ++it) {
        gemm2<256, 320, 0, true><<<gE, 256, 0, stream>>>(
            cur, alpha, edge_src, cnt_lg, bkt_lg, A1, 64, Wt_hi, E, nxt, nullptr);
        unsigned char* tmp = cur; cur = nxt; nxt = tmp;
    }
    // after 3 iters: cur == msgB, so h (r_msgA) does not alias the gather source

    // final: h = relu([alpha+node-gather(msg) | X1] @ Wt_o^T + b_o)   (fused k_mpa)
    k_x1<<<(N * 64 + 255) / 256, 256, 0, stream>>>(node_x, X1, N);     // A1 dead
    gemm2<256, 320, 1, false><<<gN, 256, 0, stream>>>(
        cur, alpha, nullptr, cnt_nd, bkt_nd, X1, 64, Wt_o, N, h, b_o);
    k_gmean<<<G, 256, 0, stream>>>(h, gstart, gcnt, (float*)d_out, G);
}

// Round 9
// 1012.817 us; speedup vs baseline: 1.5446x; 1.5446x over previous
//
#include <hip/hip_runtime.h>
#include <stdint.h>

#define HID 256
#define CAP 16

typedef __attribute__((ext_vector_type(8))) short bf16x8;   // 8 bf16 (4 VGPRs)
typedef __attribute__((ext_vector_type(4))) float f32x4;
typedef __attribute__((ext_vector_type(2))) float f32x2;
typedef __attribute__((ext_vector_type(4))) unsigned short u16x4;
typedef __attribute__((ext_vector_type(4))) unsigned char u8x4;

__device__ __forceinline__ float bf2f(unsigned short u) {
    union { unsigned int i; float f; } v; v.i = ((unsigned int)u) << 16; return v.f;
}
__device__ __forceinline__ unsigned short f2bf(float f) {
    union { float f; unsigned int i; } v; v.f = f;
    unsigned int r = (v.i + 0x7fffu + ((v.i >> 16) & 1u)) >> 16;
    return (unsigned short)r;
}
// ---- software fp8 e4m3fn fallbacks (exact w.r.t. the hw path) ----
__device__ __forceinline__ float fp82f_sw(unsigned char b) {
    unsigned int s = (unsigned int)(b & 0x80) << 24;
    int e = (b >> 3) & 0xF;
    int m = b & 7;
    float v;
    if (e) v = __uint_as_float(((unsigned int)(e + 120) << 23) | ((unsigned int)m << 20));
    else   v = (float)m * 0.001953125f;
    return __uint_as_float(__float_as_uint(v) | s);
}
__device__ __forceinline__ unsigned char f2fp8_sw(float x) {
    unsigned int bits = __float_as_uint(x);
    unsigned char s = (unsigned char)((bits >> 24) & 0x80);
    float ax = fabsf(x);
    if (!(ax >= 0.001953125f)) {
        int n = (int)rintf(ax * 512.f);
        return s | (unsigned char)n;
    }
    if (ax >= 448.f) return s | 0x7E;
    int ex; float mant = frexpf(ax, &ex);
    int e = ex + 6;
    if (e >= 1) {
        int q = (int)rintf(mant * 16.f);
        if (q == 16) { q = 8; ++e; }
        if (e > 15 || (e == 15 && q > 14)) return s | 0x7E;
        return s | (unsigned char)((e << 3) | (q - 8));
    } else {
        int n = (int)rintf(ax * 512.f);
        if (n >= 8) return s | 0x08;
        return s | (unsigned char)n;
    }
}
// ---- hardware fp8 conversion (gfx950: OCP e4m3fn) ----
__device__ __forceinline__ unsigned char f2fp8(float x) {
#if __has_builtin(__builtin_amdgcn_cvt_pk_fp8_f32)
    return (unsigned char)(__builtin_amdgcn_cvt_pk_fp8_f32(x, x, 0, false) & 0xff);
#else
    return f2fp8_sw(x);
#endif
}
__device__ __forceinline__ f32x4 fp8x4_to_f32(unsigned int u) {
#if __has_builtin(__builtin_amdgcn_cvt_pk_f32_fp8)
    f32x2 a = __builtin_amdgcn_cvt_pk_f32_fp8(u, false);
    f32x2 b = __builtin_amdgcn_cvt_pk_f32_fp8(u, true);
    f32x4 r; r[0] = a.x; r[1] = a.y; r[2] = b.x; r[3] = b.y;
    return r;
#else
    f32x4 r;
    #pragma unroll
    for (int q = 0; q < 4; ++q) r[q] = fp82f_sw((u >> (8 * q)) & 0xff);
    return r;
#endif
}
// 8 fp8 bytes -> 8 bf16 (exact: every e4m3fn value is representable in bf16)
__device__ __forceinline__ bf16x8 fp8x8_to_bf16x8(uint2 raw) {
#if __has_builtin(__builtin_amdgcn_cvt_pk_f32_fp8)
    f32x2 p0 = __builtin_amdgcn_cvt_pk_f32_fp8(raw.x, false);
    f32x2 p1 = __builtin_amdgcn_cvt_pk_f32_fp8(raw.x, true);
    f32x2 p2 = __builtin_amdgcn_cvt_pk_f32_fp8(raw.y, false);
    f32x2 p3 = __builtin_amdgcn_cvt_pk_f32_fp8(raw.y, true);
    union { unsigned int u[4]; bf16x8 v; } cv;
    cv.u[0] = (__float_as_uint(p0.x) >> 16) | (__float_as_uint(p0.y) & 0xffff0000u);
    cv.u[1] = (__float_as_uint(p1.x) >> 16) | (__float_as_uint(p1.y) & 0xffff0000u);
    cv.u[2] = (__float_as_uint(p2.x) >> 16) | (__float_as_uint(p2.y) & 0xffff0000u);
    cv.u[3] = (__float_as_uint(p3.x) >> 16) | (__float_as_uint(p3.y) & 0xffff0000u);
    return cv.v;
#else
    union { unsigned short u[8]; bf16x8 v; } cv;
    #pragma unroll
    for (int q = 0; q < 4; ++q) cv.u[q]     = f2bf(fp82f_sw((raw.x >> (8 * q)) & 0xff));
    #pragma unroll
    for (int q = 0; q < 4; ++q) cv.u[4 + q] = f2bf(fp82f_sw((raw.y >> (8 * q)) & 0xff));
    return cv.v;
#endif
}

// ---------------- utility / prep kernels ----------------

__global__ void k_zero_f(float* __restrict__ p, size_t n) {
    size_t i = (size_t)blockIdx.x * 256 + threadIdx.x;
    if (i < n) p[i] = 0.f;
}
__global__ void k_diag(float* __restrict__ out, float v) {
    if (blockIdx.x == 0 && threadIdx.x == 0) out[0] = v;
}

// one-shot init: zero na (fp32 N*HID), cnt_lg[E], cnt_nd[N], gcnt[G]; gstart[G]=N
__global__ void k_init(float* __restrict__ na, size_t nna,
                       int* __restrict__ cnt_lg, int E,
                       int* __restrict__ cnt_nd, int N,
                       int* __restrict__ gcnt, int* __restrict__ gstart, int G) {
    size_t i = (size_t)blockIdx.x * 256 + threadIdx.x;
    if (i < nna) na[i] = 0.f;
    if (i < (size_t)E) cnt_lg[i] = 0;
    if (i < (size_t)N) cnt_nd[i] = 0;
    if (i < (size_t)G) { gcnt[i] = 0; gstart[i] = N; }
}

// node_alpha[tgt[t]] += tree_mess[t]
__global__ void k_scatter_alpha(const float* __restrict__ tm, const int* __restrict__ tgt,
                                float* __restrict__ na, int T) {
    int t = blockIdx.x;
    if (t >= T) return;
    int c = threadIdx.x;
    atomicAdd(&na[(size_t)tgt[t] * HID + c], tm[(size_t)t * HID + c]);
}

__global__ void k_f2fp8(const float* __restrict__ in, unsigned char* __restrict__ out, size_t n) {
    size_t i = (size_t)blockIdx.x * 256 + threadIdx.x;
    if (i < n) out[i] = f2fp8(in[i]);
}

// Wt_i[n][k] (256 x 64): k<40 -> W_i[k][n], else 0   (bf16)
__global__ void k_wt_i(const float* __restrict__ W, unsigned short* __restrict__ Wt) {
    int i = blockIdx.x * 256 + threadIdx.x;   // 256*64
    int n = i >> 6, k = i & 63;
    Wt[i] = f2bf((k < 40) ? W[k * HID + n] : 0.f);
}
// Wt_hi[n][k] (256 x 320): k<256 -> W_h[k][n]; k-256<40 -> W_i[k-256][n]; else 0
__global__ void k_wt_hi(const float* __restrict__ Wh, const float* __restrict__ Wi,
                        unsigned short* __restrict__ Wt) {
    int i = blockIdx.x * 256 + threadIdx.x;   // 256*320
    int n = i / 320, k = i % 320;
    float v;
    if (k < 256) v = Wh[(size_t)k * HID + n];
    else if (k < 296) v = Wi[(size_t)(k - 256) * HID + n];
    else v = 0.f;
    Wt[i] = f2bf(v);
}
// Wt_o[n][k] (256 x 320): k<256 -> W_o[35+k][n]; k-256<35 -> W_o[k-256][n]; else 0
__global__ void k_wt_o(const float* __restrict__ W, unsigned short* __restrict__ Wt) {
    int i = blockIdx.x * 256 + threadIdx.x;   // 256*320
    int n = i / 320, k = i % 320;
    float v;
    if (k < 256) v = W[(size_t)(35 + k) * HID + n];
    else if (k < 291) v = W[(size_t)(k - 256) * HID + n];
    else v = 0.f;
    Wt[i] = f2bf(v);
}

// A1[e][0..63] fp8: k<35 node_x[src][k], 35..39 bond_x[e][k-35], else 0
__global__ void k_a1(const float* __restrict__ nx, const float* __restrict__ bx,
                     const int* __restrict__ esrc, unsigned char* __restrict__ A1, int E) {
    int i = blockIdx.x * 256 + threadIdx.x;
    if (i >= E * 64) return;
    int e = i >> 6, k = i & 63;
    float v = 0.f;
    if (k < 35) v = nx[(size_t)esrc[e] * 35 + k];
    else if (k < 40) v = bx[(size_t)e * 5 + (k - 35)];
    A1[i] = f2fp8(v);
}

// X1[v][0..63] fp8: k<35 node_x[v][k], else 0
__global__ void k_x1(const float* __restrict__ nx, unsigned char* __restrict__ X1, int N) {
    int i = blockIdx.x * 256 + threadIdx.x;
    if (i >= N * 64) return;
    int v = i >> 6, k = i & 63;
    X1[i] = f2fp8((k < 35) ? nx[(size_t)v * 35 + k] : 0.f);
}

// bucket fill
__global__ void k_fill(const int* __restrict__ dst, const int* __restrict__ val,
                       int* __restrict__ cnt, int* __restrict__ bkt, int n, int useval) {
    int i = blockIdx.x * 256 + threadIdx.x;
    if (i >= n) return;
    int d = dst[i];
    int p = atomicAdd(&cnt[d], 1);
    if (p < CAP) bkt[(size_t)d * CAP + p] = useval ? val[i] : i;
}

__global__ void k_gfill(const int* __restrict__ gid, int* __restrict__ gstart,
                        int* __restrict__ gcnt, int N) {
    int i = blockIdx.x * 256 + threadIdx.x;
    if (i >= N) return;
    int g = gid[i];
    atomicAdd(&gcnt[g], 1);
    atomicMin(&gstart[g], i);
}

// ---------------- split-A GEMM, fp8/bf16 A operands (R7 structure) ----------------
// C[M,256] = [Ap (K1 cols) | Aq (KTOT-K1 cols)] @ B[256][KTOT]^T   (B bf16)
// 128x128 tile, 4 waves 2x2, 4x4 of 16x16x32 bf16 MFMAs, BK=64.
// LDS rows padded to 72 elements (144 B -> 2-way bank aliasing = free).
// Register prefetch of tile kc+1 overlaps tile kc's MFMA phase.
// EPI 0: relu(C); EPI 1: relu(C + bias[col]).  OUTF8: store fp8 else bf16.
template<int K1, int KTOT, int EPI, bool PF8, bool QF8, bool OUTF8>
__global__ __launch_bounds__(256)
void gemm2(const void* __restrict__ Ap, int lda1,
           const void* __restrict__ Aq, int lda2,
           const unsigned short* __restrict__ B, int M,
           void* __restrict__ out, const float* __restrict__ bias)
{
    constexpr int NKC = KTOT / 64;
    constexpr int LDP = 72;
    __shared__ unsigned short Als[128 * LDP];
    __shared__ unsigned short Bls[128 * LDP];
    const int tid  = threadIdx.x;
    const int lane = tid & 63;
    const int wid  = tid >> 6;
    const int wm = wid & 1, wn = wid >> 1;
    const int row0 = blockIdx.x * 128;
    const int col0 = blockIdx.y * 128;
    const int l15  = lane & 15;
    const int quad = lane >> 4;

    f32x4 acc[4][4] = {};

    const int sr = tid >> 3;          // 0..31
    const int sc = (tid & 7) * 8;     // element col within 64

    bf16x8 pa[4], pb[4];
    auto loadAB = [&](int kc) {
        const bool pPart = (kc * 64 < K1);
        const void* As = pPart ? Ap : Aq;
        const int  lda  = pPart ? lda1 : lda2;
        const int  kofs = pPart ? kc * 64 : kc * 64 - K1;
        const bool f8   = pPart ? PF8 : QF8;
        #pragma unroll
        for (int t = 0; t < 4; ++t) {
            int ar = row0 + t * 32 + sr; if (ar > M - 1) ar = M - 1;
            if (f8) {
                uint2 raw = *(const uint2*)((const unsigned char*)As + (size_t)ar * lda + kofs + sc);
                pa[t] = fp8x8_to_bf16x8(raw);
            } else {
                pa[t] = *(const bf16x8*)((const unsigned short*)As + (size_t)ar * lda + kofs + sc);
            }
            pb[t] = *(const bf16x8*)(B + (size_t)(col0 + t * 32 + sr) * KTOT + kc * 64 + sc);
        }
    };

    loadAB(0);
    #pragma unroll
    for (int kc = 0; kc < NKC; ++kc) {
        #pragma unroll
        for (int t = 0; t < 4; ++t) {
            *(bf16x8*)&Als[(t * 32 + sr) * LDP + sc] = pa[t];
            *(bf16x8*)&Bls[(t * 32 + sr) * LDP + sc] = pb[t];
        }
        __syncthreads();
        if (kc + 1 < NKC) loadAB(kc + 1);   // prefetch overlaps MFMA below
        #pragma unroll
        for (int kk = 0; kk < 64; kk += 32) {
            bf16x8 af[4], bfr[4];
            #pragma unroll
            for (int i = 0; i < 4; ++i)
                af[i] = *(const bf16x8*)&Als[(wm * 64 + i * 16 + l15) * LDP + kk + quad * 8];
            #pragma unroll
            for (int j = 0; j < 4; ++j)
                bfr[j] = *(const bf16x8*)&Bls[(wn * 64 + j * 16 + l15) * LDP + kk + quad * 8];
            #pragma unroll
            for (int i = 0; i < 4; ++i)
                #pragma unroll
                for (int j = 0; j < 4; ++j)
                    acc[i][j] = __builtin_amdgcn_mfma_f32_16x16x32_bf16(af[i], bfr[j], acc[i][j], 0, 0, 0);
        }
        __syncthreads();
    }

    // epilogue: C/D layout col = lane&15, row = quad*4 + reg
    #pragma unroll
    for (int i = 0; i < 4; ++i) {
        int rbase = row0 + wm * 64 + i * 16 + quad * 4;
        #pragma unroll
        for (int r = 0; r < 4; ++r) {
            int row = rbase + r;
            if (row >= M) continue;
            #pragma unroll
            for (int j = 0; j < 4; ++j) {
                int col = col0 + wn * 64 + j * 16 + l15;
                float v = acc[i][j][r];
                if (EPI == 1) v += bias[col];
                v = v > 0.f ? v : 0.f;
                if (OUTF8) ((unsigned char*)out)[(size_t)row * HID + col] = f2fp8(v);
                else       ((unsigned short*)out)[(size_t)row * HID + col] = f2bf(v);
            }
        }
    }
}

// ---------------- gather kernels: 2 edges per wave, 8B per lane ----------------
// Each half-wave (32 lanes x 8B) covers one 256B fp8 row; a wave keeps
// ~10 independent row-loads in flight (2 edges x (alpha + 4 msg rows)).

// accum[e] = alpha[esrc[e]] + sum_{j in bkt[e]} msg[j]   (fp8 out)
__global__ void k_accum(const unsigned char* __restrict__ msg, const unsigned char* __restrict__ alpha,
                        const int* __restrict__ esrc, const int* __restrict__ cnt,
                        const int* __restrict__ bkt, unsigned char* __restrict__ accum, int E)
{
    int wave = threadIdx.x >> 6;
    int lane = threadIdx.x & 63;
    int sub  = lane >> 5;            // 0/1: which edge in this wave
    int sl   = lane & 31;
    int e = blockIdx.x * 8 + wave * 2 + sub;
    if (e >= E) return;
    int c = sl * 8;
    int src = esrc[e];
    int d = cnt[e]; if (d > CAP) d = CAP;
    uint2 au = *(const uint2*)(alpha + (size_t)src * HID + c);
    f32x4 s0 = fp8x4_to_f32(au.x);
    f32x4 s1 = fp8x4_to_f32(au.y);
    const int* bb = bkt + (size_t)e * CAP;
    for (int base = 0; base < d; base += 4) {
        int4 bi = *(const int4*)(bb + base);
        int rem = d - base;
        int i0 = bi.x;
        int i1 = (rem > 1) ? bi.y : bi.x;
        int i2 = (rem > 2) ? bi.z : bi.x;
        int i3 = (rem > 3) ? bi.w : bi.x;
        uint2 m0 = *(const uint2*)(msg + (size_t)i0 * HID + c);
        uint2 m1 = *(const uint2*)(msg + (size_t)i1 * HID + c);
        uint2 m2 = *(const uint2*)(msg + (size_t)i2 * HID + c);
        uint2 m3 = *(const uint2*)(msg + (size_t)i3 * HID + c);
        {   f32x4 vx = fp8x4_to_f32(m0.x), vy = fp8x4_to_f32(m0.y);
            #pragma unroll
            for (int k = 0; k < 4; ++k) { s0[k] += vx[k]; s1[k] += vy[k]; } }
        if (rem > 1) { f32x4 vx = fp8x4_to_f32(m1.x), vy = fp8x4_to_f32(m1.y);
            #pragma unroll
            for (int k = 0; k < 4; ++k) { s0[k] += vx[k]; s1[k] += vy[k]; } }
        if (rem > 2) { f32x4 vx = fp8x4_to_f32(m2.x), vy = fp8x4_to_f32(m2.y);
            #pragma unroll
            for (int k = 0; k < 4; ++k) { s0[k] += vx[k]; s1[k] += vy[k]; } }
        if (rem > 3) { f32x4 vx = fp8x4_to_f32(m3.x), vy = fp8x4_to_f32(m3.y);
            #pragma unroll
            for (int k = 0; k < 4; ++k) { s0[k] += vx[k]; s1[k] += vy[k]; } }
    }
    union { unsigned char b[8]; uint2 u; } ov;
    #pragma unroll
    for (int k = 0; k < 4; ++k) { ov.b[k] = f2fp8(s0[k]); ov.b[4 + k] = f2fp8(s1[k]); }
    *(uint2*)(accum + (size_t)e * HID + c) = ov.u;
}

// Mb[v] = alpha[v] + sum_{e in bkt_nd[v]} msg[e]   (bf16 out)
__global__ void k_mpa(const unsigned char* __restrict__ msg, const unsigned char* __restrict__ alpha,
                      const int* __restrict__ cnt, const int* __restrict__ bkt,
                      unsigned short* __restrict__ Mb, int N)
{
    int wave = threadIdx.x >> 6;
    int lane = threadIdx.x & 63;
    int sub  = lane >> 5;
    int sl   = lane & 31;
    int v = blockIdx.x * 8 + wave * 2 + sub;
    if (v >= N) return;
    int c = sl * 8;
    int d = cnt[v]; if (d > CAP) d = CAP;
    uint2 au = *(const uint2*)(alpha + (size_t)v * HID + c);
    f32x4 s0 = fp8x4_to_f32(au.x);
    f32x4 s1 = fp8x4_to_f32(au.y);
    const int* bb = bkt + (size_t)v * CAP;
    for (int base = 0; base < d; base += 4) {
        int4 bi = *(const int4*)(bb + base);
        int rem = d - base;
        int i0 = bi.x;
        int i1 = (rem > 1) ? bi.y : bi.x;
        int i2 = (rem > 2) ? bi.z : bi.x;
        int i3 = (rem > 3) ? bi.w : bi.x;
        uint2 m0 = *(const uint2*)(msg + (size_t)i0 * HID + c);
        uint2 m1 = *(const uint2*)(msg + (size_t)i1 * HID + c);
        uint2 m2 = *(const uint2*)(msg + (size_t)i2 * HID + c);
        uint2 m3 = *(const uint2*)(msg + (size_t)i3 * HID + c);
        {   f32x4 vx = fp8x4_to_f32(m0.x), vy = fp8x4_to_f32(m0.y);
            #pragma unroll
            for (int k = 0; k < 4; ++k) { s0[k] += vx[k]; s1[k] += vy[k]; } }
        if (rem > 1) { f32x4 vx = fp8x4_to_f32(m1.x), vy = fp8x4_to_f32(m1.y);
            #pragma unroll
            for (int k = 0; k < 4; ++k) { s0[k] += vx[k]; s1[k] += vy[k]; } }
        if (rem > 2) { f32x4 vx = fp8x4_to_f32(m2.x), vy = fp8x4_to_f32(m2.y);
            #pragma unroll
            for (int k = 0; k < 4; ++k) { s0[k] += vx[k]; s1[k] += vy[k]; } }
        if (rem > 3) { f32x4 vx = fp8x4_to_f32(m3.x), vy = fp8x4_to_f32(m3.y);
            #pragma unroll
            for (int k = 0; k < 4; ++k) { s0[k] += vx[k]; s1[k] += vy[k]; } }
    }
    union { unsigned short h[8]; uint4 u; } ov;
    #pragma unroll
    for (int k = 0; k < 4; ++k) { ov.h[k] = f2bf(s0[k]); ov.h[4 + k] = f2bf(s1[k]); }
    *(uint4*)(Mb + (size_t)v * HID + c) = ov.u;
}

// per-graph mean (graph_ids sorted -> contiguous rows)
__global__ void k_gmean(const unsigned short* __restrict__ h, const int* __restrict__ gstart,
                        const int* __restrict__ gcnt, float* __restrict__ out, int G) {
    int g = blockIdx.x;
    int c = threadIdx.x;
    int st = gstart[g], n = gcnt[g];
    float s = 0.f;
    for (int r = 0; r < n; ++r) s += bf2f(h[(size_t)(st + r) * HID + c]);
    out[(size_t)g * HID + c] = (n > 0) ? s / (float)n : 0.f;
}

// ---------------- launch ----------------
extern "C" void kernel_launch(void* const* d_in, const int* in_sizes, int n_in,
                              void* d_out, int out_size, void* d_ws, size_t ws_size,
                              hipStream_t stream)
{
    const float* node_x    = (const float*)d_in[0];
    const float* bond_x    = (const float*)d_in[1];
    const float* tree_mess = (const float*)d_in[2];
    const float* W_i       = (const float*)d_in[3];
    const float* W_h       = (const float*)d_in[4];
    const float* W_o       = (const float*)d_in[5];
    const float* b_o       = (const float*)d_in[6];
    const int* edge_src    = (const int*)d_in[7];
    const int* edge_dst    = (const int*)d_in[8];
    const int* lg_src      = (const int*)d_in[9];
    const int* lg_dst      = (const int*)d_in[10];
    const int* tgt_nodes   = (const int*)d_in[11];
    const int* graph_ids   = (const int*)d_in[12];

    const int N = in_sizes[0] / 35;
    const int E = in_sizes[1] / 5;
    const int T = in_sizes[2] / HID;
    const int L = in_sizes[9];
    const int G = out_size / HID;

    auto rup = [](size_t b) { return (b + 255) & ~(size_t)255; };
    const size_t szAcc = (size_t)E * HID;        // accum fp8
    const size_t szMsg = (size_t)E * HID;        // msg fp8
    const size_t szMbN = (size_t)N * HID * 2;    // Mb/h bf16
    const size_t R_acc = rup(szAcc > szMbN ? szAcc : szMbN);
    const size_t R_msg = rup(szMsg > szMbN ? szMsg : szMbN);
    const size_t R_al  = rup((size_t)N * HID);   // alpha fp8
    const size_t R_a1  = rup((size_t)E * 64);    // A1/X1 fp8
    const size_t need = R_acc + R_msg + R_al + R_a1
        + rup(256 * 64 * 2) + rup((size_t)256 * 320 * 2) * 2
        + rup((size_t)E * 4) + rup((size_t)E * CAP * 4)
        + rup((size_t)N * 4) + rup((size_t)N * CAP * 4)
        + rup((size_t)G * 4) * 2;
    // na (fp32, N*HID*4) aliases R_acc+R_msg (adjacent, 2*E*HID >= N*HID*4)

    if (need > ws_size) {
        k_zero_f<<<(out_size + 255) / 256, 256, 0, stream>>>((float*)d_out, (size_t)out_size);
        k_diag<<<1, 64, 0, stream>>>((float*)d_out, (float)(ws_size >> 20));
        return;
    }

    char* w = (char*)d_ws;
    auto alloc = [&](size_t bytes) { char* p = w; w += (bytes + 255) & ~(size_t)255; return p; };
    char* r_acc = (char*)alloc(R_acc);
    char* r_msg = (char*)alloc(R_msg);
    char* r_al  = (char*)alloc(R_al);
    char* r_a1  = (char*)alloc(R_a1);
    unsigned short* Wt_i  = (unsigned short*)alloc(256 * 64 * 2);
    unsigned short* Wt_hi = (unsigned short*)alloc((size_t)256 * 320 * 2);
    unsigned short* Wt_o  = (unsigned short*)alloc((size_t)256 * 320 * 2);
    int* cnt_lg = (int*)alloc((size_t)E * 4);
    int* bkt_lg = (int*)alloc((size_t)E * CAP * 4);
    int* cnt_nd = (int*)alloc((size_t)N * 4);
    int* bkt_nd = (int*)alloc((size_t)N * CAP * 4);
    int* gstart = (int*)alloc((size_t)G * 4);
    int* gcnt   = (int*)alloc((size_t)G * 4);

    float*          na    = (float*)r_acc;             // spans r_acc..r_msg (adjacent)
    unsigned char*  accum = (unsigned char*)r_acc;
    unsigned short* Mb    = (unsigned short*)r_acc;
    unsigned char*  msg   = (unsigned char*)r_msg;
    unsigned short* h     = (unsigned short*)r_msg;
    unsigned char*  alpha = (unsigned char*)r_al;
    unsigned char*  A1    = (unsigned char*)r_a1;
    unsigned char*  X1    = (unsigned char*)r_a1;

    // ---- init (single merged kernel) ----
    k_init<<<(int)(((size_t)N * HID + 255) / 256), 256, 0, stream>>>(
        na, (size_t)N * HID, cnt_lg, E, cnt_nd, N, gcnt, gstart, G);

    k_wt_i<<<64, 256, 0, stream>>>(W_i, Wt_i);
    k_wt_hi<<<320, 256, 0, stream>>>(W_h, W_i, Wt_hi);
    k_wt_o<<<320, 256, 0, stream>>>(W_o, Wt_o);
    k_scatter_alpha<<<T, 256, 0, stream>>>(tree_mess, tgt_nodes, na, T);
    k_fill<<<(L + 255) / 256, 256, 0, stream>>>(lg_dst, lg_src, cnt_lg, bkt_lg, L, 1);
    k_fill<<<(E + 255) / 256, 256, 0, stream>>>(edge_dst, (const int*)nullptr, cnt_nd, bkt_nd, E, 0);
    k_gfill<<<(N + 255) / 256, 256, 0, stream>>>(graph_ids, gstart, gcnt, N);
    k_f2fp8<<<(int)(((size_t)N * HID + 255) / 256), 256, 0, stream>>>(na, alpha, (size_t)N * HID);
    k_a1<<<(E * 64 + 255) / 256, 256, 0, stream>>>(node_x, bond_x, edge_src, A1, E);
    // na now dead; accum/msg regions free

    dim3 gE((E + 127) / 128, 2), gN((N + 127) / 128, 2);

    // msg0 = relu(A1 @ W_i)   [fp8 out]
    gemm2<0, 64, 0, false, true, true><<<gE, 256, 0, stream>>>(nullptr, 0, A1, 64, Wt_i, E, msg, nullptr);

    // 3 loopy-BP iters: accum = alpha[src] + gather(msg); msg = relu([accum|A1] @ Wt_hi^T)
    for (int it = 0; it < 3; ++it) {
        k_accum<<<(E + 7) / 8, 256, 0, stream>>>(msg, alpha, edge_src, cnt_lg, bkt_lg, accum, E);
        gemm2<256, 320, 0, true, true, true><<<gE, 256, 0, stream>>>(accum, 256, A1, 64, Wt_hi, E, msg, nullptr);
    }

    // final: Mb = alpha + node-gather(msg) [bf16]; X1 = node_x pad; h = relu([Mb|X1] @ Wt_o^T + b_o)
    k_x1<<<(N * 64 + 255) / 256, 256, 0, stream>>>(node_x, X1, N);                 // A1 dead
    k_mpa<<<(N + 7) / 8, 256, 0, stream>>>(msg, alpha, cnt_nd, bkt_nd, Mb, N);     // accum dead
    gemm2<256, 320, 1, false, true, false><<<gN, 256, 0, stream>>>(Mb, 256, X1, 64, Wt_o, N, h, b_o); // msg dead
    k_gmean<<<G, 256, 0, stream>>>(h, gstart, gcnt, (float*)d_out, G);
}